// Round 12
// baseline (218.323 us; speedup 1.0000x reference)
//
#include <hip/hip_runtime.h>
#include <hip/hip_bf16.h>

#define B_ROWS 4096
#define NROWS  8192   // 2B
#define D      256
#define NSEG   64     // segments per strip-pair  (R7: 32)
#define NBLK2  1024   // 16 pairs * 64 segments   (R7: 512)
#define TT     264    // 32-col tiles per strip-pair

typedef __attribute__((ext_vector_type(8))) short bf16x8;
typedef __attribute__((ext_vector_type(4))) float floatx4;

// ---------------------------------------------------------------------------
// Kernel 1: fused normalize + pos + selfdot + zero-init rowsum/out/counter.
// (proven: absmax 0.0 in R7)
// ---------------------------------------------------------------------------
__global__ __launch_bounds__(256) void norm_pos_kernel(
    const float* __restrict__ xi, const float* __restrict__ xj,
    short* __restrict__ z, float* __restrict__ pos,
    float* __restrict__ selfdot, float* __restrict__ rowsum,
    float* __restrict__ out, unsigned int* __restrict__ counter) {
    int gt = blockIdx.x * 256 + threadIdx.x;
    if (gt < NROWS) rowsum[gt] = 0.f;
    if (gt == 0) { out[0] = 0.f; counter[0] = 0u; }

    int p    = blockIdx.x * 4 + (threadIdx.x >> 6);
    int lane = threadIdx.x & 63;
    float4 v1 = ((const float4*)(xi + (size_t)p * D))[lane];
    float4 v2 = ((const float4*)(xj + (size_t)p * D))[lane];
    float ss1 = v1.x * v1.x + v1.y * v1.y + v1.z * v1.z + v1.w * v1.w;
    float ss2 = v2.x * v2.x + v2.y * v2.y + v2.z * v2.z + v2.w * v2.w;
#pragma unroll
    for (int off = 32; off > 0; off >>= 1) {
        ss1 += __shfl_xor(ss1, off);
        ss2 += __shfl_xor(ss2, off);
    }
    float sc1 = 1.0f / fmaxf(sqrtf(ss1), 1e-12f);
    float sc2 = 1.0f / fmaxf(sqrtf(ss2), 1e-12f);

    union { __hip_bfloat16 h[4]; short4 s4; } u1, u2;
    u1.h[0] = __float2bfloat16(v1.x * sc1); u1.h[1] = __float2bfloat16(v1.y * sc1);
    u1.h[2] = __float2bfloat16(v1.z * sc1); u1.h[3] = __float2bfloat16(v1.w * sc1);
    u2.h[0] = __float2bfloat16(v2.x * sc2); u2.h[1] = __float2bfloat16(v2.y * sc2);
    u2.h[2] = __float2bfloat16(v2.z * sc2); u2.h[3] = __float2bfloat16(v2.w * sc2);
    ((short4*)(z + (size_t)p * D))[lane]            = u1.s4;
    ((short4*)(z + (size_t)(p + B_ROWS) * D))[lane] = u2.s4;

    float sd1 = 0.f, sd2 = 0.f, dp = 0.f;
#pragma unroll
    for (int j = 0; j < 4; j++) {
        float a = __bfloat162float(u1.h[j]);
        float b = __bfloat162float(u2.h[j]);
        sd1 += a * a; sd2 += b * b; dp += a * b;
    }
#pragma unroll
    for (int off = 32; off > 0; off >>= 1) {
        sd1 += __shfl_xor(sd1, off);
        sd2 += __shfl_xor(sd2, off);
        dp  += __shfl_xor(dp,  off);
    }
    if (lane == 0) {
        pos[p] = dp; pos[p + B_ROWS] = dp;
        selfdot[p] = sd1; selfdot[p + B_ROWS] = sd2;
    }
}

// ---------------------------------------------------------------------------
// Kernel 2: R7's proven structure, unchanged except NSEG 32->64 and
// __launch_bounds__(256,3). Strip-pair s pairs panel s with panel 31-s;
// 264 32-col tiles over 64 segments (~4 tiles/block). A panel re-read from
// L1/L2 per tile (compiler remat — embraced, panel is 32 KB bf16, L1/L2-hot).
// B tiles (32 cols x 256 K = 16 KB) double-buffered in LDS.
// ---------------------------------------------------------------------------
__global__ __launch_bounds__(256, 3) void sim_rowsum_kernel(
    const short* __restrict__ z, float* __restrict__ rowsum,
    const float* __restrict__ pos, const float* __restrict__ selfdot,
    unsigned int* __restrict__ counter, float* __restrict__ out) {
    __shared__ __align__(16) short Bbuf[2][8192];   // 2 x 16 KB
    __shared__ unsigned int done_s;
    __shared__ float sdata[4];

    const int tid  = threadIdx.x;
    const int lane = tid & 63;
    const int w    = tid >> 6;
    const int lm   = lane & 15;
    const int lg   = lane >> 4;

    const int s  = blockIdx.x / NSEG;       // strip-pair 0..15
    const int q  = blockIdx.x % NSEG;       // segment
    const int L0 = 256 - 8 * s;             // tiles in first strip (panel s)
    const int cb = (q * TT) / NSEG;
    const int ce = ((q + 1) * TT) / NSEG;

    // staging geometry
    const int scol = tid >> 3;          // 0..31
    const int sg   = tid & 7;
    const int sxor = scol & 7;

    // fragment-read xor term
    const int fxor = lm & 7;

    bf16x8 a[8][4];                     // A panel: 64 rows x 256 K
    floatx4 acc[4][2];
    float rsacc[4][4];
    bf16x8 pf[4];

#pragma unroll
    for (int mi = 0; mi < 4; mi++)
#pragma unroll
        for (int r = 0; r < 4; r++) rsacc[mi][r] = 0.f;

    auto decode = [&](int c, int& panel, int& colbase, bool& mirror) {
        int cloc;
        if (c < L0) { panel = s;      cloc = c; }
        else        { panel = 31 - s; cloc = c - L0; }
        colbase = panel * 256 + cloc * 32;
        mirror  = (cloc >= 8);
    };

    auto loadA = [&](int panel) {
#pragma unroll
        for (int kk = 0; kk < 8; kk++)
#pragma unroll
            for (int mi = 0; mi < 4; mi++)
                a[kk][mi] = *(const bf16x8*)(
                    z + (size_t)(panel * 256 + w * 64 + mi * 16 + lm) * D +
                    kk * 32 + lg * 8);
    };

    auto flushRs = [&](int panel) {
#pragma unroll
        for (int mi = 0; mi < 4; mi++)
#pragma unroll
            for (int r = 0; r < 4; r++) {
                float v = rsacc[mi][r];
                v += __shfl_xor(v, 1); v += __shfl_xor(v, 2);
                v += __shfl_xor(v, 4); v += __shfl_xor(v, 8);
                if (lm == 0)
                    atomicAdd(&rowsum[panel * 256 + w * 64 + mi * 16 + lg * 4 + r], v);
                rsacc[mi][r] = 0.f;
            }
    };

    auto fetch = [&](int colbase) {
        const short* p = z + (size_t)(colbase + scol) * D + sg * 8;
#pragma unroll
        for (int j = 0; j < 4; j++) pf[j] = *(const bf16x8*)(p + j * 64);
    };
    auto writeB = [&](int buf) {
#pragma unroll
        for (int j = 0; j < 4; j++) {
            int u = scol * 32 + ((sg + 8 * j) ^ sxor);
            *(bf16x8*)(&Bbuf[buf][u * 8]) = pf[j];
        }
    };

    // ---- prologue: stage first tile, load A panel ----
    int panel, colbase; bool mirror;
    decode(cb, panel, colbase, mirror);
    int curpanel = panel;
    fetch(colbase);
    writeB(0);
    loadA(panel);
    __syncthreads();

    for (int c = cb; c < ce; c++) {
        const int buf = (c - cb) & 1;
        decode(c, panel, colbase, mirror);

        const bool hn = (c + 1 < ce);
        if (hn) {
            int npanel, ncolbase; bool nm;
            decode(c + 1, npanel, ncolbase, nm);
            fetch(ncolbase);
        }
        if (panel != curpanel) {      // strip change (≤1 per block)
            flushRs(curpanel);
            loadA(panel);
            curpanel = panel;
        }

#pragma unroll
        for (int mi = 0; mi < 4; mi++)
#pragma unroll
            for (int ni = 0; ni < 2; ni++)
                acc[mi][ni] = (floatx4){0.f, 0.f, 0.f, 0.f};

#pragma unroll
        for (int kk = 0; kk < 8; kk++) {
            bf16x8 b0 = *(const bf16x8*)(
                &Bbuf[buf][(( (0 * 16 + lm) * 32) + ((kk * 4 + lg) ^ fxor)) * 8]);
            bf16x8 b1 = *(const bf16x8*)(
                &Bbuf[buf][(( (1 * 16 + lm) * 32) + ((kk * 4 + lg) ^ fxor)) * 8]);
#pragma unroll
            for (int mi = 0; mi < 4; mi++)
                acc[mi][0] = __builtin_amdgcn_mfma_f32_16x16x32_bf16(
                    a[kk][mi], b0, acc[mi][0], 0, 0, 0);
#pragma unroll
            for (int mi = 0; mi < 4; mi++)
                acc[mi][1] = __builtin_amdgcn_mfma_f32_16x16x32_bf16(
                    a[kk][mi], b1, acc[mi][1], 0, 0, 0);
        }

        // epilogue: exp(2*sim) -> register row-sums (+ mirror col-sums)
        float cs0 = 0.f, cs1 = 0.f;
#pragma unroll
        for (int mi = 0; mi < 4; mi++)
#pragma unroll
            for (int r = 0; r < 4; r++) {
                float e0 = __expf(2.0f * acc[mi][0][r]);
                float e1 = __expf(2.0f * acc[mi][1][r]);
                rsacc[mi][r] += e0 + e1;
                cs0 += e0; cs1 += e1;
            }
        if (mirror) {
            cs0 += __shfl_xor(cs0, 16); cs0 += __shfl_xor(cs0, 32);
            cs1 += __shfl_xor(cs1, 16); cs1 += __shfl_xor(cs1, 32);
            if (lane < 16) {
                atomicAdd(&rowsum[colbase + lane],      cs0);
                atomicAdd(&rowsum[colbase + 16 + lane], cs1);
            }
        }

        if (hn) {
            writeB(buf ^ 1);
            __syncthreads();
        }
    }
    flushRs(curpanel);

    // ---- last-block-done: final loss ----
    __syncthreads();
    if (tid == 0) {
        __threadfence();
        done_s = atomicAdd(counter, 1u);
    }
    __syncthreads();
    if (done_s == (unsigned int)(NBLK2 - 1)) {
        __threadfence();
        float acc_l = 0.f;
#pragma unroll 4
        for (int r = tid; r < NROWS; r += 256) {
            float rsv = __hip_atomic_load(&rowsum[r], __ATOMIC_RELAXED,
                                          __HIP_MEMORY_SCOPE_AGENT);
            float denom = rsv - __expf(2.0f * selfdot[r]);
            acc_l += -2.0f * pos[r] + logf(denom);
        }
#pragma unroll
        for (int off = 32; off > 0; off >>= 1) acc_l += __shfl_xor(acc_l, off);
        if (lane == 0) sdata[w] = acc_l;
        __syncthreads();
        if (tid == 0)
            out[0] = (sdata[0] + sdata[1] + sdata[2] + sdata[3]) / (float)NROWS;
    }
}

// ---------------------------------------------------------------------------
extern "C" void kernel_launch(void* const* d_in, const int* in_sizes, int n_in,
                              void* d_out, int out_size, void* d_ws, size_t ws_size,
                              hipStream_t stream) {
    const float* xi = (const float*)d_in[0];
    const float* xj = (const float*)d_in[1];
    float* out      = (float*)d_out;

    char* ws       = (char*)d_ws;
    short* z       = (short*)ws;                             // 4 MiB
    float* rowsum  = (float*)(ws + (size_t)NROWS * D * 2);   // 32 KiB
    float* pos     = rowsum + NROWS;                         // 32 KiB
    float* selfdot = pos + NROWS;                            // 32 KiB
    unsigned int* counter = (unsigned int*)(selfdot + NROWS);

    norm_pos_kernel<<<B_ROWS / 4, 256, 0, stream>>>(xi, xj, z, pos, selfdot,
                                                    rowsum, out, counter);
    sim_rowsum_kernel<<<NBLK2, 256, 0, stream>>>(z, rowsum, pos, selfdot,
                                                 counter, out);
}